// Round 10
// baseline (240.761 us; speedup 1.0000x reference)
//
#include <hip/hip_runtime.h>
#include <hip/hip_fp16.h>

#define N_NODES 50000
#define N_EDGES 800000
#define IN_F 128
#define HID 128
#define NCLS 47
#define H2S 48          // padded H2 row stride (halfs)
#define W2C 64          // padded W2 col count
#define NCH 196         // scan chunks (256 nodes each)
#define TM 32           // rows per block in register-tiled GEMMs
#define XTS 40          // LDS stride for staged X^T
#define NB 64           // edge chunks per side
#define CHUNK 12500     // edges per chunk (NB*CHUNK == N_EDGES)
#define PDW 12500       // dwords per chunk histogram (u8 x 4 nodes = 50000 bytes)
#define HHALF 6250      // dwords per hist half-job (25 KB LDS)
#define FQ 3125         // dwords per fill quarter-job (12.5 KB LDS)
#define NHIST 256       // hist jobs: 2 sides x 2 halves x NB chunks
#define MEGA_LDS 25088  // dyn LDS: max(hist 25000, gemm1 20480)

// u8 packing safety: per-chunk per-node counts <= ~10 (12500 random edges /
// 50000 nodes) and total degrees <= ~55 — all << 255, so packed-u8 dwords
// add with NO cross-byte carries; plain 32-bit adds do 4-lane prefix sums.

struct __align__(8)  h2x2 { __half2 a, b; };
struct __align__(16) h2x4 { __half2 a, b, c, d; };

// ---------------------------------------------------------------------------
// mega1: blocks [0,NHIST) build LDS-privatized u8-packed half-histograms;
// blocks [NHIST,...) run gemm1 (H1h = fp16(X @ W1), UNSCALED — ns applied
// per-edge in gather1; no dependency, overlaps hist).
__global__ __launch_bounds__(256) void mega1_kernel(const int* __restrict__ ei,
                                                    unsigned int* __restrict__ Pdst,
                                                    unsigned int* __restrict__ Psrc,
                                                    const float* __restrict__ X,
                                                    const float* __restrict__ W1,
                                                    __half* __restrict__ H1h) {
    extern __shared__ __align__(16) char smem[];
    const int t = threadIdx.x;
    if (blockIdx.x < NHIST) {
        // ---- histogram role: one (side, half, chunk) job, u8 counters ----
        unsigned int* h = (unsigned int*)smem;       // HHALF dwords = 25 KB
        const int job = blockIdx.x;
        const bool is_src = job >= NHIST / 2;
        const int half = (job >> 6) & 1;
        const int chunk = job & (NB - 1);
        const int* ids = is_src ? ei : ei + N_EDGES;
        uint2* h2 = (uint2*)h;
        for (int j = t; j < HHALF / 2; j += 256) h2[j] = make_uint2(0u, 0u);
        __syncthreads();
        const int e0 = chunk * CHUNK;
        const int lo = half * HHALF;                 // dword offset of this half
        for (int k = t; k < CHUNK; k += 256) {
            int v = ids[e0 + k];
            int rel = (v >> 2) - lo;
            if ((unsigned)rel < HHALF)
                atomicAdd(&h[rel], 1u << ((v & 3) * 8));
        }
        __syncthreads();
        unsigned int* P = (is_src ? Psrc : Pdst) + (size_t)chunk * PDW + lo;
        uint2* P2 = (uint2*)P;
        for (int j = t; j < HHALF / 2; j += 256) P2[j] = h2[j];
    } else {
        // ---- gemm1 role: 32 rows x 128 cols per block, 256 threads ----
        float* xs = (float*)smem;                    // IN_F * XTS floats (20 KB)
        const int row0 = (blockIdx.x - NHIST) * TM;
#pragma unroll
        for (int i = 0; i < 4; ++i) {
            int id = t + 256 * i;                    // 0..1023
            int r = id & 31;
            int q = id >> 5;                         // 0..31: cols 4q..4q+3
            int row = row0 + r;
            float4 v = make_float4(0.f, 0.f, 0.f, 0.f);
            if (row < N_NODES) v = *(const float4*)&X[(size_t)row * IN_F + 4 * q];
            xs[(4 * q + 0) * XTS + r] = v.x;
            xs[(4 * q + 1) * XTS + r] = v.y;
            xs[(4 * q + 2) * XTS + r] = v.z;
            xs[(4 * q + 3) * XTS + r] = v.w;
        }
        __syncthreads();
        const int c = t & 31;                        // cols 4c..4c+3
        const int rg = t >> 5;                       // rows 4rg..4rg+3 (0..7)
        float acc[4][4] = {{0.f}};
#pragma unroll 4
        for (int k = 0; k < IN_F; ++k) {
            const float4 w4 = *(const float4*)&W1[k * HID + 4 * c];
            const float4 a4 = *(const float4*)&xs[k * XTS + 4 * rg];
            const float wv[4] = {w4.x, w4.y, w4.z, w4.w};
            const float av[4] = {a4.x, a4.y, a4.z, a4.w};
#pragma unroll
            for (int i = 0; i < 4; ++i)
#pragma unroll
                for (int j = 0; j < 4; ++j)
                    acc[i][j] += av[i] * wv[j];
        }
#pragma unroll
        for (int i = 0; i < 4; ++i) {
            int row = row0 + 4 * rg + i;
            if (row < N_NODES) {
                h2x2 p = {__floats2half2_rn(acc[i][0], acc[i][1]),
                          __floats2half2_rn(acc[i][2], acc[i][3])};
                *(h2x2*)&H1h[(size_t)row * HID + 4 * c] = p;
            }
        }
    }
}

// reduce: packed-u8 exclusive chunk-scan of Pdst (plain 32-bit adds — no
// carries possible), total counts -> cnt_in + norms, per-256-node chunk sums.
// One thread per dword column (4 nodes); 49 blocks x 256.
__global__ __launch_bounds__(256) void reduce_kernel(unsigned int* __restrict__ Pdst,
                                                     const unsigned int* __restrict__ Psrc,
                                                     int* __restrict__ cnt_in,
                                                     float* __restrict__ norm_src,
                                                     float* __restrict__ norm_dst,
                                                     int* __restrict__ chunk_sums) {
    __shared__ int sm[256];
    const int t = threadIdx.x;
    const int j = blockIdx.x * 256 + t;
    int tot = 0;
    if (j < PDW) {
        unsigned int run = 0;
        for (int b = 0; b < NB; ++b) {
            unsigned int v = Pdst[(size_t)b * PDW + j];
            Pdst[(size_t)b * PDW + j] = run;         // exclusive prefix (packed u8)
            run += v;                                // byte-wise, carry-free
        }
        int n0 = run & 0xff, n1 = (run >> 8) & 0xff;
        int n2 = (run >> 16) & 0xff, n3 = (run >> 24) & 0xff;
        *(int4*)&cnt_in[4 * j] = make_int4(n0, n1, n2, n3);
        *(float4*)&norm_dst[4 * j] = make_float4(
            rsqrtf(fmaxf((float)n0, 1.0f)), rsqrtf(fmaxf((float)n1, 1.0f)),
            rsqrtf(fmaxf((float)n2, 1.0f)), rsqrtf(fmaxf((float)n3, 1.0f)));
        tot = n0 + n1 + n2 + n3;
        unsigned int rs = 0;
        for (int b = 0; b < NB; ++b) rs += Psrc[(size_t)b * PDW + j];
        int s0 = rs & 0xff, s1 = (rs >> 8) & 0xff;
        int s2 = (rs >> 16) & 0xff, s3 = (rs >> 24) & 0xff;
        *(float4*)&norm_src[4 * j] = make_float4(
            rsqrtf(fmaxf((float)s0, 1.0f)), rsqrtf(fmaxf((float)s1, 1.0f)),
            rsqrtf(fmaxf((float)s2, 1.0f)), rsqrtf(fmaxf((float)s3, 1.0f)));
    }
    sm[t] = tot;
    __syncthreads();
    const int g = t & 63;                            // 64 threads = 256 nodes
    for (int off = 32; off > 0; off >>= 1) {
        if (g < off) sm[t] += sm[t + off];
        __syncthreads();
    }
    if (g == 0) chunk_sums[blockIdx.x * 4 + (t >> 6)] = sm[t];
}

// offsets: each block recomputes the chunk base from chunk_sums then scans
// its 256 nodes. Block 0 also pads W2 -> W2p.
__global__ __launch_bounds__(256) void scan3_kernel(const int* __restrict__ cnt_in,
                                                    const int* __restrict__ chunk_sums,
                                                    int* __restrict__ offsets,
                                                    const float* __restrict__ W2,
                                                    float* __restrict__ W2p) {
    __shared__ int sm[256];
    const int t = threadIdx.x;
    int v = (t < NCH) ? chunk_sums[t] : 0;
    sm[t] = v;
    __syncthreads();
    for (int off = 1; off < 256; off <<= 1) {
        int u = (t >= off) ? sm[t - off] : 0;
        __syncthreads();
        sm[t] += u;
        __syncthreads();
    }
    const int basev = (blockIdx.x == 0) ? 0 : sm[blockIdx.x - 1];
    __syncthreads();
    const int idx = blockIdx.x * 256 + t;
    int c = (idx < N_NODES) ? cnt_in[idx] : 0;
    sm[t] = c;
    __syncthreads();
    for (int off = 1; off < 256; off <<= 1) {
        int u = (t >= off) ? sm[t - off] : 0;
        __syncthreads();
        sm[t] += u;
        __syncthreads();
    }
    if (idx < N_NODES) offsets[idx] = basev + sm[t] - c;
    if (blockIdx.x == 0) {
        if (t == 0) offsets[N_NODES] = N_EDGES;
        for (int i2 = t; i2 < HID * W2C; i2 += 256) {
            int k = i2 >> 6, cc = i2 & 63;
            W2p[i2] = (cc < NCLS) ? W2[k * NCLS + cc] : 0.f;
        }
    }
}

// fill: job = (node-quarter, chunk); u8-packed LDS cursors (12.5 KB).
// rank = own byte of returning LDS atomic; base = byte from scanned Pdst.
__global__ __launch_bounds__(256) void fill_kernel(const int* __restrict__ src,
                                                   const int* __restrict__ dst,
                                                   const int* __restrict__ offsets,
                                                   const unsigned int* __restrict__ Pdst,
                                                   int* __restrict__ csr_src) {
    __shared__ unsigned int cur[FQ];          // 12.5 KB packed u8 cursors
    const int quarter = blockIdx.x >> 6;      // 0..3
    const int chunk = blockIdx.x & (NB - 1);
    for (int j = threadIdx.x; j < FQ; j += 256) cur[j] = 0u;
    __syncthreads();
    const unsigned int* base = Pdst + (size_t)chunk * PDW;
    const int e0 = chunk * CHUNK;
    const int lo = quarter * FQ;
    for (int k = threadIdx.x; k < CHUNK; k += 256) {
        int d = dst[e0 + k];
        int rel = (d >> 2) - lo;
        if ((unsigned)rel < FQ) {
            const int sh = (d & 3) * 8;
            unsigned int old = atomicAdd(&cur[rel], 1u << sh);
            unsigned int rank = (old >> sh) & 0xffu;
            unsigned int bh = (base[d >> 2] >> sh) & 0xffu;
            csr_src[offsets[d] + (int)bh + (int)rank] = src[e0 + k];
        }
    }
}

// --- gather1: Hrelu16[row,:] = fp16(relu((sum ns[s]*H1h[s,:])*nd + b1)*ns) -
// one node per wave; 4 edges per iter (16 lanes x 16B each), 16-edge unroll.
// Invalid tail lanes carry ns=0 so no tail branches are needed.
__global__ __launch_bounds__(256) void gather1_kernel(const __half* __restrict__ H1h,
        const int* __restrict__ offsets, const int* __restrict__ csr_src,
        const float* __restrict__ b1, const float* __restrict__ norm_src,
        const float* __restrict__ norm_dst, __half* __restrict__ Hrelu16) {
    const int lane = threadIdx.x & 63;
    const int q = lane >> 4;              // edge slot 0..3
    const int fl = lane & 15;             // features 8*fl .. 8*fl+7
    const int row = blockIdx.x * 4 + (threadIdx.x >> 6);
    const int beg = offsets[row], end = offsets[row + 1];
    float a0 = 0.f, a1 = 0.f, a2 = 0.f, a3 = 0.f;
    float a4 = 0.f, a5 = 0.f, a6 = 0.f, a7 = 0.f;
    for (int base = beg; base < end; base += 64) {
        int idx = 0;
        float nsv = 0.f;
        if (base + lane < end) {
            idx = csr_src[base + lane];
            nsv = norm_src[idx];
        }
        const int cnt = min(end - base, 64);
        for (int j = 0; j < cnt; j += 16) {
            int e0 = j + q, e1 = j + 4 + q, e2 = j + 8 + q, e3 = j + 12 + q;
            int s0 = __shfl(idx, e0);  float n0 = __shfl(nsv, e0);
            int s1 = __shfl(idx, e1);  float n1 = __shfl(nsv, e1);
            int s2 = __shfl(idx, e2);  float n2 = __shfl(nsv, e2);
            int s3 = __shfl(idx, e3);  float n3 = __shfl(nsv, e3);
            h2x4 v0 = *(const h2x4*)&H1h[(size_t)s0 * HID + 8 * fl];
            h2x4 v1 = *(const h2x4*)&H1h[(size_t)s1 * HID + 8 * fl];
            h2x4 v2 = *(const h2x4*)&H1h[(size_t)s2 * HID + 8 * fl];
            h2x4 v3 = *(const h2x4*)&H1h[(size_t)s3 * HID + 8 * fl];
            float2 f;
            f = __half22float2(v0.a); a0 = fmaf(f.x, n0, a0); a1 = fmaf(f.y, n0, a1);
            f = __half22float2(v0.b); a2 = fmaf(f.x, n0, a2); a3 = fmaf(f.y, n0, a3);
            f = __half22float2(v0.c); a4 = fmaf(f.x, n0, a4); a5 = fmaf(f.y, n0, a5);
            f = __half22float2(v0.d); a6 = fmaf(f.x, n0, a6); a7 = fmaf(f.y, n0, a7);
            f = __half22float2(v1.a); a0 = fmaf(f.x, n1, a0); a1 = fmaf(f.y, n1, a1);
            f = __half22float2(v1.b); a2 = fmaf(f.x, n1, a2); a3 = fmaf(f.y, n1, a3);
            f = __half22float2(v1.c); a4 = fmaf(f.x, n1, a4); a5 = fmaf(f.y, n1, a5);
            f = __half22float2(v1.d); a6 = fmaf(f.x, n1, a6); a7 = fmaf(f.y, n1, a7);
            f = __half22float2(v2.a); a0 = fmaf(f.x, n2, a0); a1 = fmaf(f.y, n2, a1);
            f = __half22float2(v2.b); a2 = fmaf(f.x, n2, a2); a3 = fmaf(f.y, n2, a3);
            f = __half22float2(v2.c); a4 = fmaf(f.x, n2, a4); a5 = fmaf(f.y, n2, a5);
            f = __half22float2(v2.d); a6 = fmaf(f.x, n2, a6); a7 = fmaf(f.y, n2, a7);
            f = __half22float2(v3.a); a0 = fmaf(f.x, n3, a0); a1 = fmaf(f.y, n3, a1);
            f = __half22float2(v3.b); a2 = fmaf(f.x, n3, a2); a3 = fmaf(f.y, n3, a3);
            f = __half22float2(v3.c); a4 = fmaf(f.x, n3, a4); a5 = fmaf(f.y, n3, a5);
            f = __half22float2(v3.d); a6 = fmaf(f.x, n3, a6); a7 = fmaf(f.y, n3, a7);
        }
    }
    a0 += __shfl_xor(a0, 16); a1 += __shfl_xor(a1, 16);
    a2 += __shfl_xor(a2, 16); a3 += __shfl_xor(a3, 16);
    a4 += __shfl_xor(a4, 16); a5 += __shfl_xor(a5, 16);
    a6 += __shfl_xor(a6, 16); a7 += __shfl_xor(a7, 16);
    a0 += __shfl_xor(a0, 32); a1 += __shfl_xor(a1, 32);
    a2 += __shfl_xor(a2, 32); a3 += __shfl_xor(a3, 32);
    a4 += __shfl_xor(a4, 32); a5 += __shfl_xor(a5, 32);
    a6 += __shfl_xor(a6, 32); a7 += __shfl_xor(a7, 32);
    if (lane < 16) {
        float nd = norm_dst[row], ns = norm_src[row];
        float4 bA = *(const float4*)&b1[8 * fl];
        float4 bB = *(const float4*)&b1[8 * fl + 4];
        float o0 = fmaxf(fmaf(a0, nd, bA.x), 0.f) * ns;
        float o1 = fmaxf(fmaf(a1, nd, bA.y), 0.f) * ns;
        float o2 = fmaxf(fmaf(a2, nd, bA.z), 0.f) * ns;
        float o3 = fmaxf(fmaf(a3, nd, bA.w), 0.f) * ns;
        float o4 = fmaxf(fmaf(a4, nd, bB.x), 0.f) * ns;
        float o5 = fmaxf(fmaf(a5, nd, bB.y), 0.f) * ns;
        float o6 = fmaxf(fmaf(a6, nd, bB.z), 0.f) * ns;
        float o7 = fmaxf(fmaf(a7, nd, bB.w), 0.f) * ns;
        h2x4 p = {__floats2half2_rn(o0, o1), __floats2half2_rn(o2, o3),
                  __floats2half2_rn(o4, o5), __floats2half2_rn(o6, o7)};
        *(h2x4*)&Hrelu16[(size_t)row * HID + 8 * fl] = p;
    }
}

// --- gemm2: H2h[row, 0..47] = fp16( Hrelu16[row,:] @ W2p ), 32 rows/block --
__global__ __launch_bounds__(128) void gemm2_kernel(const __half* __restrict__ Hrelu16,
                                                    const float* __restrict__ W2p,
                                                    __half* __restrict__ H2h) {
    __shared__ __align__(16) float xs[HID * XTS];
    const int t = threadIdx.x;
    const int row0 = blockIdx.x * TM;
#pragma unroll
    for (int i = 0; i < 4; ++i) {
        int id = t + 128 * i;            // 0..511
        int r = id & 31;
        int g = id >> 5;                 // 0..15: cols 8g..8g+7
        int row = row0 + r;
        h2x4 v{};
        if (row < N_NODES) v = *(const h2x4*)&Hrelu16[(size_t)row * HID + 8 * g];
        float2 f0 = __half22float2(v.a), f1 = __half22float2(v.b);
        float2 f2 = __half22float2(v.c), f3 = __half22float2(v.d);
        xs[(8 * g + 0) * XTS + r] = f0.x;
        xs[(8 * g + 1) * XTS + r] = f0.y;
        xs[(8 * g + 2) * XTS + r] = f1.x;
        xs[(8 * g + 3) * XTS + r] = f1.y;
        xs[(8 * g + 4) * XTS + r] = f2.x;
        xs[(8 * g + 5) * XTS + r] = f2.y;
        xs[(8 * g + 6) * XTS + r] = f3.x;
        xs[(8 * g + 7) * XTS + r] = f3.y;
    }
    __syncthreads();
    const int c = t & 15;
    const int rg = t >> 4;
    float acc[4][4] = {{0.f}};
#pragma unroll 4
    for (int k = 0; k < HID; ++k) {
        const float4 w4 = *(const float4*)&W2p[k * W2C + 4 * c];
        const float4 a4 = *(const float4*)&xs[k * XTS + 4 * rg];
        const float wv[4] = {w4.x, w4.y, w4.z, w4.w};
        const float av[4] = {a4.x, a4.y, a4.z, a4.w};
#pragma unroll
        for (int i = 0; i < 4; ++i)
#pragma unroll
            for (int j = 0; j < 4; ++j)
                acc[i][j] += av[i] * wv[j];
    }
    if (c < 12) {
#pragma unroll
        for (int i = 0; i < 4; ++i) {
            int row = row0 + 4 * rg + i;
            if (row < N_NODES) {
                h2x2 p = {__floats2half2_rn(acc[i][0], acc[i][1]),
                          __floats2half2_rn(acc[i][2], acc[i][3])};
                *(h2x2*)&H2h[(size_t)row * H2S + 4 * c] = p;
            }
        }
    }
}

// --- gather2: out[row,c] = (sum H2h[s,c])*nd + b2[c]; weight-masked tail ---
__global__ __launch_bounds__(256) void gather2_kernel(const __half* __restrict__ H2h,
        const int* __restrict__ offsets, const int* __restrict__ csr_src,
        const float* __restrict__ b2, const float* __restrict__ norm_dst,
        float* __restrict__ out) {
    const int lane = threadIdx.x & 63;
    const int row = blockIdx.x * 4 + (threadIdx.x >> 6);
    const int beg = offsets[row], end = offsets[row + 1];
    const int cl = min(lane, H2S - 1);
    float acc = 0.f;
    for (int base = beg; base < end; base += 64) {
        int idx = 0;
        float wv = 0.f;
        if (base + lane < end) {
            idx = csr_src[base + lane];
            wv = 1.f;
        }
        const int cnt = min(end - base, 64);
        for (int j = 0; j < cnt; j += 4) {
            int s0 = __shfl(idx, j);     float w0 = __shfl(wv, j);
            int s1 = __shfl(idx, j + 1); float w1 = __shfl(wv, j + 1);
            int s2 = __shfl(idx, j + 2); float w2 = __shfl(wv, j + 2);
            int s3 = __shfl(idx, j + 3); float w3 = __shfl(wv, j + 3);
            float f0 = __half2float(H2h[(size_t)s0 * H2S + cl]);
            float f1 = __half2float(H2h[(size_t)s1 * H2S + cl]);
            float f2 = __half2float(H2h[(size_t)s2 * H2S + cl]);
            float f3 = __half2float(H2h[(size_t)s3 * H2S + cl]);
            acc = fmaf(f0, w0, acc);
            acc = fmaf(f1, w1, acc);
            acc = fmaf(f2, w2, acc);
            acc = fmaf(f3, w3, acc);
        }
    }
    if (lane < NCLS) out[(size_t)row * NCLS + lane] = acc * norm_dst[row] + b2[lane];
}

// ---------------------------------------------------------------------------
extern "C" void kernel_launch(void* const* d_in, const int* in_sizes, int n_in,
                              void* d_out, int out_size, void* d_ws, size_t ws_size,
                              hipStream_t stream) {
    const float* X  = (const float*)d_in[0];
    const int*   ei = (const int*)d_in[1];
    const float* W1 = (const float*)d_in[2];
    const float* b1 = (const float*)d_in[3];
    const float* W2 = (const float*)d_in[4];
    const float* b2 = (const float*)d_in[5];
    float* out = (float*)d_out;

    const int* src = ei;
    const int* dst = ei + N_EDGES;

    char* w = (char*)d_ws;
    auto alloc = [&](size_t bytes) {
        char* p = w;
        w += (bytes + 255) & ~(size_t)255;
        return p;
    };
    float*  norm_src   = (float*)alloc(N_NODES * 4);
    float*  norm_dst   = (float*)alloc(N_NODES * 4);
    int*    cnt_in     = (int*)alloc(N_NODES * 4);
    int*    offsets    = (int*)alloc((N_NODES + 1) * 4);
    int*    csr_src    = (int*)alloc((size_t)N_EDGES * 4);
    int*    chunk_sums = (int*)alloc(NCH * 4);
    float*  W2p        = (float*)alloc((size_t)HID * W2C * 4);
    __half* H1h        = (__half*)alloc((size_t)N_NODES * HID * 2);   // 12.8 MB
    __half* Hrelu16    = (__half*)alloc((size_t)N_NODES * HID * 2);   // 12.8 MB
    __half* H2h        = (__half*)alloc((size_t)N_NODES * H2S * 2);   //  4.8 MB
    unsigned int* Pdst = (unsigned int*)alloc((size_t)NB * PDW * 4);  //  3.2 MB
    unsigned int* Psrc = (unsigned int*)alloc((size_t)NB * PDW * 4);  //  3.2 MB

    const int gemm_blocks = (N_NODES + TM - 1) / TM;                  // 1563
    mega1_kernel<<<NHIST + gemm_blocks, 256, MEGA_LDS, stream>>>(ei, Pdst, Psrc,
                                                                 X, W1, H1h);
    reduce_kernel<<<(PDW + 255) / 256, 256, 0, stream>>>(Pdst, Psrc, cnt_in,
                                                         norm_src, norm_dst, chunk_sums);
    scan3_kernel<<<NCH, 256, 0, stream>>>(cnt_in, chunk_sums, offsets, W2, W2p);
    fill_kernel<<<4 * NB, 256, 0, stream>>>(src, dst, offsets, Pdst, csr_src);

    gather1_kernel<<<N_NODES / 4, 256, 0, stream>>>(H1h, offsets, csr_src, b1,
                                                    norm_src, norm_dst, Hrelu16);
    gemm2_kernel<<<gemm_blocks, 128, 0, stream>>>(Hrelu16, W2p, H2h);
    gather2_kernel<<<N_NODES / 4, 256, 0, stream>>>(H2h, offsets, csr_src, b2,
                                                    norm_dst, out);
}

// Round 11
// 218.782 us; speedup vs baseline: 1.1005x; 1.1005x over previous
//
#include <hip/hip_runtime.h>
#include <hip/hip_fp16.h>

#define N_NODES 50000
#define N_EDGES 800000
#define IN_F 128
#define HID 128
#define NCLS 47
#define H2S 48          // padded H2 row stride (halfs)
#define W2C 64          // padded W2 col count
#define NCH 196         // scan chunks (256 nodes each)
#define TM 32           // rows per block in register-tiled GEMMs
#define XTS 40          // LDS stride for staged X^T
#define NB 64           // edge chunks per side
#define CHUNK 12500     // edges per chunk (NB*CHUNK == N_EDGES)
#define PDW 12500       // dwords per chunk histogram (u8 x 4 nodes)
#define HHALF 6250      // dwords per hist half-job (25 KB LDS)
#define FQ 3125         // dwords per fill quarter-job (12.5 KB LDS)
#define NHIST 256       // hist jobs: 2 sides x 2 halves x NB chunks
#define FG_LDS 20480    // fill+gemm1 union static LDS (gemm1 xs dominates)

// u8 packing safety: per-chunk per-node counts <= ~10 and total degrees
// <= ~55 — all << 255, so packed-u8 dwords add carry-free.

struct __align__(8)  h2x2 { __half2 a, b; };
struct __align__(16) h2x4 { __half2 a, b, c, d; };

// ---------------------------------------------------------------------------
// hist: one (side, half, chunk) u8 half-histogram per block. 512 threads to
// halve the per-block serial latency span (r10 theory: hist is chain-bound).
__global__ __launch_bounds__(512) void hist_kernel(const int* __restrict__ ei,
                                                   unsigned int* __restrict__ Pdst,
                                                   unsigned int* __restrict__ Psrc) {
    __shared__ unsigned int h[HHALF];            // 25 KB u8-packed counters
    const int t = threadIdx.x;
    const int job = blockIdx.x;
    const bool is_src = job >= NHIST / 2;
    const int half = (job >> 6) & 1;
    const int chunk = job & (NB - 1);
    const int* ids = is_src ? ei : ei + N_EDGES;
    uint2* h2 = (uint2*)h;
    for (int j = t; j < HHALF / 2; j += 512) h2[j] = make_uint2(0u, 0u);
    __syncthreads();
    const int e0 = chunk * CHUNK;
    const int lo = half * HHALF;                 // dword offset of this half
    for (int k = t; k < CHUNK; k += 512) {
        int v = ids[e0 + k];
        int rel = (v >> 2) - lo;
        if ((unsigned)rel < HHALF)
            atomicAdd(&h[rel], 1u << ((v & 3) * 8));
    }
    __syncthreads();
    unsigned int* P = (is_src ? Psrc : Pdst) + (size_t)chunk * PDW + lo;
    uint2* P2 = (uint2*)P;
    for (int j = t; j < HHALF / 2; j += 512) P2[j] = h2[j];
}

// reduce: packed-u8 exclusive chunk-scan of Pdst (carry-free 32-bit adds),
// totals -> cnt_in + norms, per-256-node chunk sums.
__global__ __launch_bounds__(256) void reduce_kernel(unsigned int* __restrict__ Pdst,
                                                     const unsigned int* __restrict__ Psrc,
                                                     int* __restrict__ cnt_in,
                                                     float* __restrict__ norm_src,
                                                     float* __restrict__ norm_dst,
                                                     int* __restrict__ chunk_sums) {
    __shared__ int sm[256];
    const int t = threadIdx.x;
    const int j = blockIdx.x * 256 + t;
    int tot = 0;
    if (j < PDW) {
        unsigned int run = 0;
        for (int b = 0; b < NB; ++b) {
            unsigned int v = Pdst[(size_t)b * PDW + j];
            Pdst[(size_t)b * PDW + j] = run;         // exclusive prefix (packed u8)
            run += v;
        }
        int n0 = run & 0xff, n1 = (run >> 8) & 0xff;
        int n2 = (run >> 16) & 0xff, n3 = (run >> 24) & 0xff;
        *(int4*)&cnt_in[4 * j] = make_int4(n0, n1, n2, n3);
        *(float4*)&norm_dst[4 * j] = make_float4(
            rsqrtf(fmaxf((float)n0, 1.0f)), rsqrtf(fmaxf((float)n1, 1.0f)),
            rsqrtf(fmaxf((float)n2, 1.0f)), rsqrtf(fmaxf((float)n3, 1.0f)));
        tot = n0 + n1 + n2 + n3;
        unsigned int rs = 0;
        for (int b = 0; b < NB; ++b) rs += Psrc[(size_t)b * PDW + j];
        int s0 = rs & 0xff, s1 = (rs >> 8) & 0xff;
        int s2 = (rs >> 16) & 0xff, s3 = (rs >> 24) & 0xff;
        *(float4*)&norm_src[4 * j] = make_float4(
            rsqrtf(fmaxf((float)s0, 1.0f)), rsqrtf(fmaxf((float)s1, 1.0f)),
            rsqrtf(fmaxf((float)s2, 1.0f)), rsqrtf(fmaxf((float)s3, 1.0f)));
    }
    sm[t] = tot;
    __syncthreads();
    const int g = t & 63;                            // 64 threads = 256 nodes
    for (int off = 32; off > 0; off >>= 1) {
        if (g < off) sm[t] += sm[t + off];
        __syncthreads();
    }
    if (g == 0) chunk_sums[blockIdx.x * 4 + (t >> 6)] = sm[t];
}

// offsets: each block recomputes the chunk base from chunk_sums then scans
// its 256 nodes. Block 0 also pads W2 -> W2p.
__global__ __launch_bounds__(256) void scan3_kernel(const int* __restrict__ cnt_in,
                                                    const int* __restrict__ chunk_sums,
                                                    int* __restrict__ offsets,
                                                    const float* __restrict__ W2,
                                                    float* __restrict__ W2p) {
    __shared__ int sm[256];
    const int t = threadIdx.x;
    int v = (t < NCH) ? chunk_sums[t] : 0;
    sm[t] = v;
    __syncthreads();
    for (int off = 1; off < 256; off <<= 1) {
        int u = (t >= off) ? sm[t - off] : 0;
        __syncthreads();
        sm[t] += u;
        __syncthreads();
    }
    const int basev = (blockIdx.x == 0) ? 0 : sm[blockIdx.x - 1];
    __syncthreads();
    const int idx = blockIdx.x * 256 + t;
    int c = (idx < N_NODES) ? cnt_in[idx] : 0;
    sm[t] = c;
    __syncthreads();
    for (int off = 1; off < 256; off <<= 1) {
        int u = (t >= off) ? sm[t - off] : 0;
        __syncthreads();
        sm[t] += u;
        __syncthreads();
    }
    if (idx < N_NODES) offsets[idx] = basev + sm[t] - c;
    if (blockIdx.x == 0) {
        if (t == 0) offsets[N_NODES] = N_EDGES;
        for (int i2 = t; i2 < HID * W2C; i2 += 256) {
            int k = i2 >> 6, cc = i2 & 63;
            W2p[i2] = (cc < NCLS) ? W2[k * NCLS + cc] : 0.f;
        }
    }
}

// fill+gemm1 mega: blocks [0,4NB) scatter CSR slots (u8 cursors, 12.5 KB);
// blocks [4NB,...) run gemm1 (no deps — overlaps fill, the longest bare
// stage). Union static LDS 20 KB -> 8 blocks/CU for both roles.
__global__ __launch_bounds__(256) void fill_gemm1_kernel(const int* __restrict__ src,
        const int* __restrict__ dst, const int* __restrict__ offsets,
        const unsigned int* __restrict__ Pdst, int* __restrict__ csr_src,
        const float* __restrict__ X, const float* __restrict__ W1,
        __half* __restrict__ H1h) {
    __shared__ __align__(16) char smem[FG_LDS];
    const int t = threadIdx.x;
    if (blockIdx.x < 4 * NB) {
        // ---- fill role: (node-quarter, chunk), u8-packed LDS cursors ----
        unsigned int* cur = (unsigned int*)smem;     // FQ dwords = 12.5 KB
        const int quarter = blockIdx.x >> 6;         // 0..3
        const int chunk = blockIdx.x & (NB - 1);
        for (int j = t; j < FQ; j += 256) cur[j] = 0u;
        __syncthreads();
        const unsigned int* base = Pdst + (size_t)chunk * PDW;
        const int e0 = chunk * CHUNK;
        const int lo = quarter * FQ;
        for (int k = t; k < CHUNK; k += 256) {
            int d = dst[e0 + k];
            int rel = (d >> 2) - lo;
            if ((unsigned)rel < FQ) {
                const int sh = (d & 3) * 8;
                unsigned int old = atomicAdd(&cur[rel], 1u << sh);
                unsigned int rank = (old >> sh) & 0xffu;
                unsigned int bh = (base[d >> 2] >> sh) & 0xffu;
                csr_src[offsets[d] + (int)bh + (int)rank] = src[e0 + k];
            }
        }
    } else {
        // ---- gemm1 role: 32 rows x 128 cols per block, 256 threads ----
        float* xs = (float*)smem;                    // IN_F*XTS floats = 20 KB
        const int row0 = (blockIdx.x - 4 * NB) * TM;
#pragma unroll
        for (int i = 0; i < 4; ++i) {
            int id = t + 256 * i;                    // 0..1023
            int r = id & 31;
            int q = id >> 5;                         // 0..31: cols 4q..4q+3
            int row = row0 + r;
            float4 v = make_float4(0.f, 0.f, 0.f, 0.f);
            if (row < N_NODES) v = *(const float4*)&X[(size_t)row * IN_F + 4 * q];
            xs[(4 * q + 0) * XTS + r] = v.x;
            xs[(4 * q + 1) * XTS + r] = v.y;
            xs[(4 * q + 2) * XTS + r] = v.z;
            xs[(4 * q + 3) * XTS + r] = v.w;
        }
        __syncthreads();
        const int c = t & 31;                        // cols 4c..4c+3
        const int rg = t >> 5;                       // rows 4rg..4rg+3 (0..7)
        float acc[4][4] = {{0.f}};
#pragma unroll 4
        for (int k = 0; k < IN_F; ++k) {
            const float4 w4 = *(const float4*)&W1[k * HID + 4 * c];
            const float4 a4 = *(const float4*)&xs[k * XTS + 4 * rg];
            const float wv[4] = {w4.x, w4.y, w4.z, w4.w};
            const float av[4] = {a4.x, a4.y, a4.z, a4.w};
#pragma unroll
            for (int i = 0; i < 4; ++i)
#pragma unroll
                for (int j = 0; j < 4; ++j)
                    acc[i][j] += av[i] * wv[j];
        }
#pragma unroll
        for (int i = 0; i < 4; ++i) {
            int row = row0 + 4 * rg + i;
            if (row < N_NODES) {
                h2x2 p = {__floats2half2_rn(acc[i][0], acc[i][1]),
                          __floats2half2_rn(acc[i][2], acc[i][3])};
                *(h2x2*)&H1h[(size_t)row * HID + 4 * c] = p;
            }
        }
    }
}

// --- gather1: Hrelu16[row,:] = fp16(relu((sum ns[s]*H1h[s,:])*nd + b1)*ns) -
__global__ __launch_bounds__(256) void gather1_kernel(const __half* __restrict__ H1h,
        const int* __restrict__ offsets, const int* __restrict__ csr_src,
        const float* __restrict__ b1, const float* __restrict__ norm_src,
        const float* __restrict__ norm_dst, __half* __restrict__ Hrelu16) {
    const int lane = threadIdx.x & 63;
    const int q = lane >> 4;              // edge slot 0..3
    const int fl = lane & 15;             // features 8*fl .. 8*fl+7
    const int row = blockIdx.x * 4 + (threadIdx.x >> 6);
    const int beg = offsets[row], end = offsets[row + 1];
    float a0 = 0.f, a1 = 0.f, a2 = 0.f, a3 = 0.f;
    float a4 = 0.f, a5 = 0.f, a6 = 0.f, a7 = 0.f;
    for (int base = beg; base < end; base += 64) {
        int idx = 0;
        float nsv = 0.f;
        if (base + lane < end) {
            idx = csr_src[base + lane];
            nsv = norm_src[idx];
        }
        const int cnt = min(end - base, 64);
        for (int j = 0; j < cnt; j += 16) {
            int e0 = j + q, e1 = j + 4 + q, e2 = j + 8 + q, e3 = j + 12 + q;
            int s0 = __shfl(idx, e0);  float n0 = __shfl(nsv, e0);
            int s1 = __shfl(idx, e1);  float n1 = __shfl(nsv, e1);
            int s2 = __shfl(idx, e2);  float n2 = __shfl(nsv, e2);
            int s3 = __shfl(idx, e3);  float n3 = __shfl(nsv, e3);
            h2x4 v0 = *(const h2x4*)&H1h[(size_t)s0 * HID + 8 * fl];
            h2x4 v1 = *(const h2x4*)&H1h[(size_t)s1 * HID + 8 * fl];
            h2x4 v2 = *(const h2x4*)&H1h[(size_t)s2 * HID + 8 * fl];
            h2x4 v3 = *(const h2x4*)&H1h[(size_t)s3 * HID + 8 * fl];
            float2 f;
            f = __half22float2(v0.a); a0 = fmaf(f.x, n0, a0); a1 = fmaf(f.y, n0, a1);
            f = __half22float2(v0.b); a2 = fmaf(f.x, n0, a2); a3 = fmaf(f.y, n0, a3);
            f = __half22float2(v0.c); a4 = fmaf(f.x, n0, a4); a5 = fmaf(f.y, n0, a5);
            f = __half22float2(v0.d); a6 = fmaf(f.x, n0, a6); a7 = fmaf(f.y, n0, a7);
            f = __half22float2(v1.a); a0 = fmaf(f.x, n1, a0); a1 = fmaf(f.y, n1, a1);
            f = __half22float2(v1.b); a2 = fmaf(f.x, n1, a2); a3 = fmaf(f.y, n1, a3);
            f = __half22float2(v1.c); a4 = fmaf(f.x, n1, a4); a5 = fmaf(f.y, n1, a5);
            f = __half22float2(v1.d); a6 = fmaf(f.x, n1, a6); a7 = fmaf(f.y, n1, a7);
            f = __half22float2(v2.a); a0 = fmaf(f.x, n2, a0); a1 = fmaf(f.y, n2, a1);
            f = __half22float2(v2.b); a2 = fmaf(f.x, n2, a2); a3 = fmaf(f.y, n2, a3);
            f = __half22float2(v2.c); a4 = fmaf(f.x, n2, a4); a5 = fmaf(f.y, n2, a5);
            f = __half22float2(v2.d); a6 = fmaf(f.x, n2, a6); a7 = fmaf(f.y, n2, a7);
            f = __half22float2(v3.a); a0 = fmaf(f.x, n3, a0); a1 = fmaf(f.y, n3, a1);
            f = __half22float2(v3.b); a2 = fmaf(f.x, n3, a2); a3 = fmaf(f.y, n3, a3);
            f = __half22float2(v3.c); a4 = fmaf(f.x, n3, a4); a5 = fmaf(f.y, n3, a5);
            f = __half22float2(v3.d); a6 = fmaf(f.x, n3, a6); a7 = fmaf(f.y, n3, a7);
        }
    }
    a0 += __shfl_xor(a0, 16); a1 += __shfl_xor(a1, 16);
    a2 += __shfl_xor(a2, 16); a3 += __shfl_xor(a3, 16);
    a4 += __shfl_xor(a4, 16); a5 += __shfl_xor(a5, 16);
    a6 += __shfl_xor(a6, 16); a7 += __shfl_xor(a7, 16);
    a0 += __shfl_xor(a0, 32); a1 += __shfl_xor(a1, 32);
    a2 += __shfl_xor(a2, 32); a3 += __shfl_xor(a3, 32);
    a4 += __shfl_xor(a4, 32); a5 += __shfl_xor(a5, 32);
    a6 += __shfl_xor(a6, 32); a7 += __shfl_xor(a7, 32);
    if (lane < 16) {
        float nd = norm_dst[row], ns = norm_src[row];
        float4 bA = *(const float4*)&b1[8 * fl];
        float4 bB = *(const float4*)&b1[8 * fl + 4];
        float o0 = fmaxf(fmaf(a0, nd, bA.x), 0.f) * ns;
        float o1 = fmaxf(fmaf(a1, nd, bA.y), 0.f) * ns;
        float o2 = fmaxf(fmaf(a2, nd, bA.z), 0.f) * ns;
        float o3 = fmaxf(fmaf(a3, nd, bA.w), 0.f) * ns;
        float o4 = fmaxf(fmaf(a4, nd, bB.x), 0.f) * ns;
        float o5 = fmaxf(fmaf(a5, nd, bB.y), 0.f) * ns;
        float o6 = fmaxf(fmaf(a6, nd, bB.z), 0.f) * ns;
        float o7 = fmaxf(fmaf(a7, nd, bB.w), 0.f) * ns;
        h2x4 p = {__floats2half2_rn(o0, o1), __floats2half2_rn(o2, o3),
                  __floats2half2_rn(o4, o5), __floats2half2_rn(o6, o7)};
        *(h2x4*)&Hrelu16[(size_t)row * HID + 8 * fl] = p;
    }
}

// --- gemm2: H2h[row, 0..47] = fp16( Hrelu16[row,:] @ W2p ), 32 rows/block --
__global__ __launch_bounds__(128) void gemm2_kernel(const __half* __restrict__ Hrelu16,
                                                    const float* __restrict__ W2p,
                                                    __half* __restrict__ H2h) {
    __shared__ __align__(16) float xs[HID * XTS];
    const int t = threadIdx.x;
    const int row0 = blockIdx.x * TM;
#pragma unroll
    for (int i = 0; i < 4; ++i) {
        int id = t + 128 * i;            // 0..511
        int r = id & 31;
        int g = id >> 5;                 // 0..15: cols 8g..8g+7
        int row = row0 + r;
        h2x4 v{};
        if (row < N_NODES) v = *(const h2x4*)&Hrelu16[(size_t)row * HID + 8 * g];
        float2 f0 = __half22float2(v.a), f1 = __half22float2(v.b);
        float2 f2 = __half22float2(v.c), f3 = __half22float2(v.d);
        xs[(8 * g + 0) * XTS + r] = f0.x;
        xs[(8 * g + 1) * XTS + r] = f0.y;
        xs[(8 * g + 2) * XTS + r] = f1.x;
        xs[(8 * g + 3) * XTS + r] = f1.y;
        xs[(8 * g + 4) * XTS + r] = f2.x;
        xs[(8 * g + 5) * XTS + r] = f2.y;
        xs[(8 * g + 6) * XTS + r] = f3.x;
        xs[(8 * g + 7) * XTS + r] = f3.y;
    }
    __syncthreads();
    const int c = t & 15;
    const int rg = t >> 4;
    float acc[4][4] = {{0.f}};
#pragma unroll 4
    for (int k = 0; k < HID; ++k) {
        const float4 w4 = *(const float4*)&W2p[k * W2C + 4 * c];
        const float4 a4 = *(const float4*)&xs[k * XTS + 4 * rg];
        const float wv[4] = {w4.x, w4.y, w4.z, w4.w};
        const float av[4] = {a4.x, a4.y, a4.z, a4.w};
#pragma unroll
        for (int i = 0; i < 4; ++i)
#pragma unroll
            for (int j = 0; j < 4; ++j)
                acc[i][j] += av[i] * wv[j];
    }
    if (c < 12) {
#pragma unroll
        for (int i = 0; i < 4; ++i) {
            int row = row0 + 4 * rg + i;
            if (row < N_NODES) {
                h2x2 p = {__floats2half2_rn(acc[i][0], acc[i][1]),
                          __floats2half2_rn(acc[i][2], acc[i][3])};
                *(h2x2*)&H2h[(size_t)row * H2S + 4 * c] = p;
            }
        }
    }
}

// --- gather2: out[row,c] = (sum H2h[s,c])*nd + b2[c]; weight-masked tail ---
__global__ __launch_bounds__(256) void gather2_kernel(const __half* __restrict__ H2h,
        const int* __restrict__ offsets, const int* __restrict__ csr_src,
        const float* __restrict__ b2, const float* __restrict__ norm_dst,
        float* __restrict__ out) {
    const int lane = threadIdx.x & 63;
    const int row = blockIdx.x * 4 + (threadIdx.x >> 6);
    const int beg = offsets[row], end = offsets[row + 1];
    const int cl = min(lane, H2S - 1);
    float acc = 0.f;
    for (int base = beg; base < end; base += 64) {
        int idx = 0;
        float wv = 0.f;
        if (base + lane < end) {
            idx = csr_src[base + lane];
            wv = 1.f;
        }
        const int cnt = min(end - base, 64);
        for (int j = 0; j < cnt; j += 4) {
            int s0 = __shfl(idx, j);     float w0 = __shfl(wv, j);
            int s1 = __shfl(idx, j + 1); float w1 = __shfl(wv, j + 1);
            int s2 = __shfl(idx, j + 2); float w2 = __shfl(wv, j + 2);
            int s3 = __shfl(idx, j + 3); float w3 = __shfl(wv, j + 3);
            float f0 = __half2float(H2h[(size_t)s0 * H2S + cl]);
            float f1 = __half2float(H2h[(size_t)s1 * H2S + cl]);
            float f2 = __half2float(H2h[(size_t)s2 * H2S + cl]);
            float f3 = __half2float(H2h[(size_t)s3 * H2S + cl]);
            acc = fmaf(f0, w0, acc);
            acc = fmaf(f1, w1, acc);
            acc = fmaf(f2, w2, acc);
            acc = fmaf(f3, w3, acc);
        }
    }
    if (lane < NCLS) out[(size_t)row * NCLS + lane] = acc * norm_dst[row] + b2[lane];
}

// ---------------------------------------------------------------------------
extern "C" void kernel_launch(void* const* d_in, const int* in_sizes, int n_in,
                              void* d_out, int out_size, void* d_ws, size_t ws_size,
                              hipStream_t stream) {
    const float* X  = (const float*)d_in[0];
    const int*   ei = (const int*)d_in[1];
    const float* W1 = (const float*)d_in[2];
    const float* b1 = (const float*)d_in[3];
    const float* W2 = (const float*)d_in[4];
    const float* b2 = (const float*)d_in[5];
    float* out = (float*)d_out;

    const int* src = ei;
    const int* dst = ei + N_EDGES;

    char* w = (char*)d_ws;
    auto alloc = [&](size_t bytes) {
        char* p = w;
        w += (bytes + 255) & ~(size_t)255;
        return p;
    };
    float*  norm_src   = (float*)alloc(N_NODES * 4);
    float*  norm_dst   = (float*)alloc(N_NODES * 4);
    int*    cnt_in     = (int*)alloc(N_NODES * 4);
    int*    offsets    = (int*)alloc((N_NODES + 1) * 4);
    int*    csr_src    = (int*)alloc((size_t)N_EDGES * 4);
    int*    chunk_sums = (int*)alloc(NCH * 4);
    float*  W2p        = (float*)alloc((size_t)HID * W2C * 4);
    __half* H1h        = (__half*)alloc((size_t)N_NODES * HID * 2);   // 12.8 MB
    __half* Hrelu16    = (__half*)alloc((size_t)N_NODES * HID * 2);   // 12.8 MB
    __half* H2h        = (__half*)alloc((size_t)N_NODES * H2S * 2);   //  4.8 MB
    unsigned int* Pdst = (unsigned int*)alloc((size_t)NB * PDW * 4);  //  3.2 MB
    unsigned int* Psrc = (unsigned int*)alloc((size_t)NB * PDW * 4);  //  3.2 MB

    const int gemm_blocks = (N_NODES + TM - 1) / TM;                  // 1563
    hist_kernel<<<NHIST, 512, 0, stream>>>(ei, Pdst, Psrc);
    reduce_kernel<<<(PDW + 255) / 256, 256, 0, stream>>>(Pdst, Psrc, cnt_in,
                                                         norm_src, norm_dst, chunk_sums);
    scan3_kernel<<<NCH, 256, 0, stream>>>(cnt_in, chunk_sums, offsets, W2, W2p);
    fill_gemm1_kernel<<<4 * NB + gemm_blocks, 256, 0, stream>>>(src, dst, offsets,
                                                                Pdst, csr_src,
                                                                X, W1, H1h);
    gather1_kernel<<<N_NODES / 4, 256, 0, stream>>>(H1h, offsets, csr_src, b1,
                                                    norm_src, norm_dst, Hrelu16);
    gemm2_kernel<<<gemm_blocks, 128, 0, stream>>>(Hrelu16, W2p, H2h);
    gather2_kernel<<<N_NODES / 4, 256, 0, stream>>>(H2h, offsets, csr_src, b2,
                                                    norm_dst, out);
}